// Round 1
// 570.028 us; speedup vs baseline: 1.0173x; 1.0173x over previous
//
#include <hip/hip_runtime.h>
#include <math.h>

// ---------------------------------------------------------------------------
// TransferSH fused: per-point deg-3 SH evaluation + per-block recomputed
// per-frame affine MLP (tiny: 16->32->12, weights L2-resident).
// Single kernel: removes the serialized mlp-prologue launch and the ws
// round-trip. Streaming arrays (positions/indexes/out) use non-temporal
// loads/stores to preserve L2/L3 capacity for the 360MB higher_sh gather
// working set (random gather, ~37% repeat accesses can hit L3).
// ---------------------------------------------------------------------------

__global__ __launch_bounds__(256) void transfer_sh_fused(
    const float* __restrict__ positions,
    const int*   __restrict__ indexes,
    const float* __restrict__ cam_pos,
    const float* __restrict__ glo,
    const float* __restrict__ base_sh,
    const float* __restrict__ higher_sh,
    const float* __restrict__ w1,
    const float* __restrict__ b1,
    const float* __restrict__ ln_w,
    const float* __restrict__ ln_b,
    const float* __restrict__ w2,
    const float* __restrict__ b2,
    float* __restrict__ out,            // (N,3)
    float* __restrict__ mean_out,       // scalar tail of out buffer
    int n)
{
    __shared__ float aff[12];
    __shared__ float hsh[32];
    __shared__ float ssh[12];

    const int t = threadIdx.x;
    const int i = blockIdx.x * 256 + t;
    const bool active = (i < n);
    const int ie = active ? i : (n - 1);   // clamp so tail threads stay
                                           // barrier-safe (no early return)

    // ---- issue ALL per-point loads first: gather latency (~900cy) overlaps
    //      the per-block MLP prologue below ----
    unsigned idx = (unsigned)__builtin_nontemporal_load(indexes + ie);

    float px = __builtin_nontemporal_load(positions + 3 * ie + 0);
    float py = __builtin_nontemporal_load(positions + 3 * ie + 1);
    float pz = __builtin_nontemporal_load(positions + 3 * ie + 2);

    // base_sh gather: 3 scalar loads (12B random -> one line regardless)
    float a0 = base_sh[3 * idx + 0];
    float a1 = base_sh[3 * idx + 1];
    float a2 = base_sh[3 * idx + 2];

    // higher_sh gather: 45 floats at float-offset fo = 45*idx (4B-aligned
    // only). Read the enclosing 16B-aligned 192B window as 12 float4
    // (misalign m = fo&3 <= 3, m+45 <= 48 always covers the row).
    unsigned fo = 45u * idx;
    const float4* W = (const float4*)(higher_sh + (fo & ~3u));
    float4 v[12];
    #pragma unroll
    for (int q = 0; q < 12; ++q) v[q] = W[q];

    // ---- per-block affine MLP on wave 0 (redundant per block; weights are
    //      L2-resident, ~900 FLOPs). Lanes 0-31 own hidden units; 64-wide
    //      shuffle reduce for LayerNorm stats (lanes >=32 contribute 0). ----
    if (t < 64) {
        float h = 0.f;
        if (t < 32) {
            h = b1[t];
            #pragma unroll
            for (int k = 0; k < 16; ++k) h += glo[k] * w1[k * 32 + t];
        }
        float s = h;
        #pragma unroll
        for (int off = 32; off > 0; off >>= 1) s += __shfl_down(s, off);
        float mu = __shfl(s, 0) * (1.f / 32.f);
        float d = (t < 32) ? (h - mu) : 0.f;
        float v2 = d * d;
        #pragma unroll
        for (int off = 32; off > 0; off >>= 1) v2 += __shfl_down(v2, off);
        float var = __shfl(v2, 0) * (1.f / 32.f);
        float inv = rsqrtf(var + 1e-5f);
        if (t < 32) {
            float hv = (h - mu) * inv * ln_w[t] + ln_b[t];
            hsh[t] = hv > 0.f ? hv : 0.f;
        }
    }
    __syncthreads();
    if (t < 12) {
        float s2 = b2[t];
        #pragma unroll
        for (int j = 0; j < 32; ++j) s2 += hsh[j] * w2[j * 12 + t];
        s2 *= 1e-12f;                                 // affine_res element
        ssh[t] = fabsf(s2);
        float e = ((t & 3) == (t >> 2)) ? 1.f : 0.f;  // eye(3,4) diag 0,5,10
        aff[t] = s2 + e;
    }
    __syncthreads();
    if (blockIdx.x == 0 && t == 0) {
        float sa = 0.f;
        #pragma unroll
        for (int q2 = 0; q2 < 12; ++q2) sa += ssh[q2];
        *mean_out = sa * (1.f / 12.f);
    }

    // ---- per-point compute (loads above are completing under this) ----
    float dx = px - cam_pos[0];
    float dy = py - cam_pos[1];
    float dz = pz - cam_pos[2];
    float rn = rsqrtf(dx * dx + dy * dy + dz * dz);
    float x = dx * rn, y = dy * rn, z = dz * rn;

    float xx = x * x, yy = y * y, zz = z * z;
    float xy = x * y, yz = y * z, xz = x * z;

    // deg-3 SH basis (b[0] folded into base term below)
    float b[16];
    b[1]  = -0.4886025119029199f * y;
    b[2]  =  0.4886025119029199f * z;
    b[3]  = -0.4886025119029199f * x;
    b[4]  =  1.0925484305920792f * xy;
    b[5]  = -1.0925484305920792f * yz;
    b[6]  =  0.31539156525252005f * (2.f * zz - xx - yy);
    b[7]  = -1.0925484305920792f * xz;
    b[8]  =  0.5462742152960396f * (xx - yy);
    b[9]  = -0.5900435899266435f * y * (3.f * xx - yy);
    b[10] =  2.890611442640554f  * xy * z;
    b[11] = -0.4570457994644658f * y * (4.f * zz - xx - yy);
    b[12] =  0.3731763325901154f * z * (2.f * zz - 3.f * xx - 3.f * yy);
    b[13] = -0.4570457994644658f * x * (4.f * zz - xx - yy);
    b[14] =  1.445305721320277f  * z * (xx - yy);
    b[15] = -0.5900435899266435f * x * (xx - yy);

    const float C0 = 0.28209479177387814f;
    float c0 = a0 * C0 + 0.5f;
    float c1 = a1 * C0 + 0.5f;
    float c2 = a2 * C0 + 0.5f;

    float Wf[48];
    #pragma unroll
    for (int q = 0; q < 12; ++q) {
        Wf[4 * q + 0] = v[q].x; Wf[4 * q + 1] = v[q].y;
        Wf[4 * q + 2] = v[q].z; Wf[4 * q + 3] = v[q].w;
    }

#define ACC(M)                                      \
    {                                               \
        _Pragma("unroll")                           \
        for (int k = 0; k < 15; ++k) {              \
            c0 += Wf[(M) + k]      * b[k + 1];      \
            c1 += Wf[(M) + 15 + k] * b[k + 1];      \
            c2 += Wf[(M) + 30 + k] * b[k + 1];      \
        }                                           \
    }
    switch (fo & 3u) {
        case 0: ACC(0) break;
        case 1: ACC(1) break;
        case 2: ACC(2) break;
        default: ACC(3) break;
    }
#undef ACC

    // affine from LDS (broadcast) + clamp + nt store
    if (active) {
        #pragma unroll
        for (int r = 0; r < 3; ++r) {
            float vv = c0 * aff[4 * r + 0] + c1 * aff[4 * r + 1] +
                       c2 * aff[4 * r + 2] + aff[4 * r + 3];
            vv = fminf(fmaxf(vv, 0.f), 1.f);
            __builtin_nontemporal_store(vv, out + 3 * i + r);
        }
    }
}

extern "C" void kernel_launch(void* const* d_in, const int* in_sizes, int n_in,
                              void* d_out, int out_size, void* d_ws, size_t ws_size,
                              hipStream_t stream) {
    const float* positions = (const float*)d_in[0];
    const int*   indexes   = (const int*)d_in[1];
    const float* cam_pos   = (const float*)d_in[2];
    const float* glo       = (const float*)d_in[3];
    const float* base_sh   = (const float*)d_in[4];
    const float* higher_sh = (const float*)d_in[5];
    const float* w1        = (const float*)d_in[6];
    const float* b1        = (const float*)d_in[7];
    const float* ln_w      = (const float*)d_in[8];
    const float* ln_b      = (const float*)d_in[9];
    const float* w2        = (const float*)d_in[10];
    const float* b2        = (const float*)d_in[11];

    float* out = (float*)d_out;

    int n = in_sizes[0] / 3;                 // number of points
    float* mean_out = out + (out_size - 1);  // scalar output at tail

    int block = 256;
    int grid = (n + block - 1) / block;
    transfer_sh_fused<<<grid, block, 0, stream>>>(
        positions, indexes, cam_pos, glo, base_sh, higher_sh,
        w1, b1, ln_w, ln_b, w2, b2, out, mean_out, n);
}